// Round 1
// baseline (168.704 us; speedup 1.0000x reference)
//
#include <hip/hip_runtime.h>
#include <hip/hip_bf16.h>

#define SQ 2048
#define NH 32
#define DH 128
#define SKV 4096
#define NK 256
#define SCALE 0.08838834764831845f

typedef __attribute__((ext_vector_type(8))) __bf16 bf16x8;
typedef __attribute__((ext_vector_type(4))) float floatx4;
typedef __attribute__((ext_vector_type(4))) unsigned short ushort4_t;

// LDS strides (in elements). Pads chosen for bank behavior + 16B alignment of
// MFMA fragment reads (row byte offsets multiple of 16).
#define QS_STRIDE 136   // 128 + 8 bf16
#define KS_STRIDE 136   // 128 + 8 bf16
#define VB_STRIDE 72    // 64 + 8 bf16 (V stored transposed: [d][k_local])
#define SC_STRIDE 261   // odd -> conflict-free per-head column scans (scalar f32)
#define PB_STRIDE 264   // 256 + 8 bf16

__device__ __forceinline__ unsigned short f2bf(float x) {
  // round-to-nearest-even fp32 -> bf16 (inputs are finite normals)
  union { float f; unsigned int u; } v; v.f = x;
  unsigned int r = v.u + 0x7FFFu + ((v.u >> 16) & 1u);
  return (unsigned short)(r >> 16);
}

__global__ __launch_bounds__(256, 2) void sparse_attn_kernel(
    const float* __restrict__ q, const float* __restrict__ kv,
    const float* __restrict__ sink, const int* __restrict__ topk,
    float* __restrict__ out) {
  __shared__ unsigned short qs[NH * QS_STRIDE];          //  8704 B
  __shared__ unsigned short kvbuf[DH * VB_STRIDE];       // 18432 B (>= 64*KS_STRIDE)
  __shared__ float scores[NH * SC_STRIDE];               // 33408 B
  __shared__ unsigned short pbuf[NH * PB_STRIDE];        // 16896 B
  __shared__ float red[NH * 8];
  __shared__ float marr[NH];
  __shared__ float invd[NH];

  const int tid = threadIdx.x;
  const int s = blockIdx.x;
  const int wave = tid >> 6;
  const int lane = tid & 63;
  const int quad = lane >> 4;
  const int l16 = lane & 15;

  // ---- Phase 0: Q -> LDS as bf16, pre-scaled by SCALE ----
  {
    const float* qp = q + (size_t)s * (NH * DH);
    int h = tid >> 3;
    int d0 = (tid & 7) * 16;
    for (int i = 0; i < 4; i++) {
      float4 f = *(const float4*)(qp + h * DH + d0 + i * 4);
      ushort4_t u = { f2bf(f.x * SCALE), f2bf(f.y * SCALE),
                      f2bf(f.z * SCALE), f2bf(f.w * SCALE) };
      *(ushort4_t*)&qs[h * QS_STRIDE + d0 + i * 4] = u;
    }
  }
  __syncthreads();

  // Hoist Q A-fragments: A[m = l16][k = quad*8 + j], k-step = 32
  bf16x8 afrag[2][4];
  for (int mt = 0; mt < 2; mt++)
    for (int ks = 0; ks < 4; ks++)
      afrag[mt][ks] =
          *(const bf16x8*)&qs[(mt * 16 + l16) * QS_STRIDE + ks * 32 + quad * 8];

  const int* tks = topk + (size_t)s * NK;

  // ---- Phase 1: scores = (Q*SCALE) K_g^T, 4 chunks of 64 gathered rows ----
  for (int c = 0; c < 4; c++) {
    {  // gather K chunk -> kvbuf[r][d] bf16
      int r = tid >> 2;
      int seg = tid & 3;
      int idx = tks[c * 64 + r];
      const float* kp = kv + (size_t)idx * (2 * DH);
      int d0 = seg * 32;
      unsigned short* dst = &kvbuf[r * KS_STRIDE];
      for (int i = 0; i < 8; i++) {
        float4 f = *(const float4*)(kp + d0 + i * 4);
        ushort4_t u = { f2bf(f.x), f2bf(f.y), f2bf(f.z), f2bf(f.w) };
        *(ushort4_t*)&dst[d0 + i * 4] = u;
      }
    }
    __syncthreads();
    {  // GEMM1: wave handles n-tile (c*64 + wave*16 .. +15)
      floatx4 acc0 = {0.f, 0.f, 0.f, 0.f};
      floatx4 acc1 = {0.f, 0.f, 0.f, 0.f};
      const int nrow = wave * 16 + l16;
      for (int ks = 0; ks < 4; ks++) {
        bf16x8 b = *(const bf16x8*)&kvbuf[nrow * KS_STRIDE + ks * 32 + quad * 8];
        acc0 = __builtin_amdgcn_mfma_f32_16x16x32_bf16(afrag[0][ks], b, acc0, 0, 0, 0);
        acc1 = __builtin_amdgcn_mfma_f32_16x16x32_bf16(afrag[1][ks], b, acc1, 0, 0, 0);
      }
      int ncol = c * 64 + wave * 16 + l16;
      for (int r4 = 0; r4 < 4; r4++) {
        scores[(quad * 4 + r4) * SC_STRIDE + ncol] = acc0[r4];
        scores[(16 + quad * 4 + r4) * SC_STRIDE + ncol] = acc1[r4];
      }
    }
    __syncthreads();
  }

  // ---- Phase 2: softmax with sink; P = exp(s - m) as bf16, 1/denom saved ----
  {
    int h = tid & 31;
    int part = tid >> 5;  // 0..7, covers k = part*32 .. +31
    float mx = -3.0e38f;
    for (int k = 0; k < 32; k++)
      mx = fmaxf(mx, scores[h * SC_STRIDE + part * 32 + k]);
    red[h * 8 + part] = mx;
    __syncthreads();
    if (tid < 32) {
      float m = sink[tid];
      for (int p = 0; p < 8; p++) m = fmaxf(m, red[tid * 8 + p]);
      marr[tid] = m;
    }
    __syncthreads();
    float m = marr[h];
    float psum = 0.f;
    for (int k = 0; k < 32; k++) {
      int kk = part * 32 + k;
      float e = __expf(scores[h * SC_STRIDE + kk] - m);
      psum += e;
      pbuf[h * PB_STRIDE + kk] = f2bf(e);
    }
    red[h * 8 + part] = psum;
    __syncthreads();
    if (tid < 32) {
      float d = __expf(sink[tid] - marr[tid]);
      for (int p = 0; p < 8; p++) d += red[tid * 8 + p];
      invd[tid] = 1.0f / d;
    }
  }
  __syncthreads();

  // ---- Phase 3: O = P V_g, 4 chunks of 64; V staged transposed [d][k_local] ----
  floatx4 acc[2][2];
  for (int mt = 0; mt < 2; mt++)
    for (int nt = 0; nt < 2; nt++)
      acc[mt][nt] = (floatx4){0.f, 0.f, 0.f, 0.f};

  for (int c = 0; c < 4; c++) {
    {  // gather V chunk, transposed store (lane-per-row -> conflict-free u16 writes)
      int r = tid & 63;
      int dq = tid >> 6;
      int idx = tks[c * 64 + r];
      const float* vp = kv + (size_t)idx * (2 * DH) + DH;
      int d0 = dq * 32;
      for (int i = 0; i < 8; i++) {
        float4 f = *(const float4*)(vp + d0 + i * 4);
        int d = d0 + i * 4;
        kvbuf[(d + 0) * VB_STRIDE + r] = f2bf(f.x);
        kvbuf[(d + 1) * VB_STRIDE + r] = f2bf(f.y);
        kvbuf[(d + 2) * VB_STRIDE + r] = f2bf(f.z);
        kvbuf[(d + 3) * VB_STRIDE + r] = f2bf(f.w);
      }
    }
    __syncthreads();
    // GEMM2: wave handles d-columns [wave*32, wave*32+32)
    for (int ks = 0; ks < 2; ks++) {
      int kof = c * 64 + ks * 32 + quad * 8;
      bf16x8 a0 = *(const bf16x8*)&pbuf[l16 * PB_STRIDE + kof];
      bf16x8 a1 = *(const bf16x8*)&pbuf[(16 + l16) * PB_STRIDE + kof];
      int kl = ks * 32 + quad * 8;
      bf16x8 b0 = *(const bf16x8*)&kvbuf[(wave * 32 + l16) * VB_STRIDE + kl];
      bf16x8 b1 = *(const bf16x8*)&kvbuf[(wave * 32 + 16 + l16) * VB_STRIDE + kl];
      acc[0][0] = __builtin_amdgcn_mfma_f32_16x16x32_bf16(a0, b0, acc[0][0], 0, 0, 0);
      acc[0][1] = __builtin_amdgcn_mfma_f32_16x16x32_bf16(a0, b1, acc[0][1], 0, 0, 0);
      acc[1][0] = __builtin_amdgcn_mfma_f32_16x16x32_bf16(a1, b0, acc[1][0], 0, 0, 0);
      acc[1][1] = __builtin_amdgcn_mfma_f32_16x16x32_bf16(a1, b1, acc[1][1], 0, 0, 0);
    }
    __syncthreads();
  }

  // ---- Phase 4: epilogue: scale by 1/denom and store fp32 ----
  {
    float* op = out + (size_t)s * (NH * DH);
    for (int mt = 0; mt < 2; mt++)
      for (int nt = 0; nt < 2; nt++)
        for (int r4 = 0; r4 < 4; r4++) {
          int h = mt * 16 + quad * 4 + r4;
          int d = wave * 32 + nt * 16 + l16;
          op[h * DH + d] = acc[mt][nt][r4] * invd[h];
        }
  }
}

extern "C" void kernel_launch(void* const* d_in, const int* in_sizes, int n_in,
                              void* d_out, int out_size, void* d_ws, size_t ws_size,
                              hipStream_t stream) {
  (void)in_sizes; (void)n_in; (void)out_size; (void)d_ws; (void)ws_size;
  const float* q    = (const float*)d_in[0];
  const float* kv   = (const float*)d_in[1];
  const float* sink = (const float*)d_in[2];
  const int*   topk = (const int*)d_in[3];
  float* out = (float*)d_out;
  sparse_attn_kernel<<<dim3(SQ), dim3(256), 0, stream>>>(q, kv, sink, topk, out);
}

// Round 2
// 153.044 us; speedup vs baseline: 1.1023x; 1.1023x over previous
//
#include <hip/hip_runtime.h>
#include <hip/hip_bf16.h>

#define SQ 2048
#define NH 32
#define DH 128
#define NK 256
#define SCALE 0.08838834764831845f

typedef __attribute__((ext_vector_type(8))) __bf16 bf16x8;
typedef __attribute__((ext_vector_type(4))) float floatx4;
typedef __attribute__((ext_vector_type(4))) unsigned short ushort4_t;

// element strides
#define QS_STRIDE 136   // u16; 272 B rows -> 16B aligned, 2-way-max b128 reads (free)
#define KS_STRIDE 136   // u16
#define VB_STRIDE 72    // u16; V transposed [d][k_local]
#define PB_STRIDE 264   // u16; 528 B rows

// LDS layout (bytes), total 37504 -> 4 blocks/CU (150 KB of 160)
#define OFF_KV   16896
#define OFF_TOPK 35328
#define OFF_SINK 36352
#define OFF_RED  36480
#define OFF_RED2 36992
#define SMEM_SZ  37504

__device__ __forceinline__ unsigned short f2bf(float x) {
  union { float f; unsigned int u; } v; v.f = x;
  unsigned int r = v.u + 0x7FFFu + ((v.u >> 16) & 1u);
  return (unsigned short)(r >> 16);
}

__global__ __launch_bounds__(256, 4) void sparse_attn_kernel(
    const float* __restrict__ q, const float* __restrict__ kv,
    const float* __restrict__ sink, const int* __restrict__ topk,
    float* __restrict__ out) {
  __shared__ __align__(16) char smem[SMEM_SZ];
  unsigned short* qs    = (unsigned short*)smem;            // phase 0 only
  unsigned short* pbuf  = (unsigned short*)smem;            // softmax onward (qs dead)
  unsigned short* kvbuf = (unsigned short*)(smem + OFF_KV); // K chunk / V chunk
  int*   topk_s = (int*)(smem + OFF_TOPK);
  float* sink_s = (float*)(smem + OFF_SINK);
  float* red    = (float*)(smem + OFF_RED);
  float* red2   = (float*)(smem + OFF_RED2);

  const int tid = threadIdx.x;
  const int s = blockIdx.x;
  const int wave = tid >> 6;
  const int lane = tid & 63;
  const int quad = lane >> 4;
  const int l16 = lane & 15;

  // ---- Phase 0: topk+sink -> LDS, K chunk 0 gather, Q -> LDS bf16*SCALE ----
  topk_s[tid] = topk[(size_t)s * NK + tid];
  if (tid < 32) sink_s[tid] = sink[tid];
  {  // K chunk 0 (indices straight from global; overlaps with Q staging)
    int r = tid >> 2, seg = tid & 3;
    int idx = topk[(size_t)s * NK + r];
    const float* kp = kv + (size_t)idx * (2 * DH);
    int d0 = seg * 32;
    unsigned short* dst = &kvbuf[r * KS_STRIDE];
#pragma unroll
    for (int i = 0; i < 8; i++) {
      float4 f = *(const float4*)(kp + d0 + i * 4);
      ushort4_t u = { f2bf(f.x), f2bf(f.y), f2bf(f.z), f2bf(f.w) };
      *(ushort4_t*)&dst[d0 + i * 4] = u;
    }
  }
  {  // Q stage (pre-scaled)
    const float* qp = q + (size_t)s * (NH * DH);
    int h = tid >> 3;
    int d0 = (tid & 7) * 16;
#pragma unroll
    for (int i = 0; i < 4; i++) {
      float4 f = *(const float4*)(qp + h * DH + d0 + i * 4);
      ushort4_t u = { f2bf(f.x * SCALE), f2bf(f.y * SCALE),
                      f2bf(f.z * SCALE), f2bf(f.w * SCALE) };
      *(ushort4_t*)&qs[h * QS_STRIDE + d0 + i * 4] = u;
    }
  }
  __syncthreads();

  // Hoist Q A-fragments: A[m=l16][k=quad*8+j]; qs dead afterwards
  bf16x8 afrag[2][4];
#pragma unroll
  for (int mt = 0; mt < 2; mt++)
#pragma unroll
    for (int ks = 0; ks < 4; ks++)
      afrag[mt][ks] =
          *(const bf16x8*)&qs[(mt * 16 + l16) * QS_STRIDE + ks * 32 + quad * 8];

  // ---- Phase 1: GEMM1, scores kept in registers (C-layout) ----
  floatx4 sc[4][2];
#pragma unroll 1
  for (int c = 0; c < 4; c++) {
    floatx4 a0 = {0.f, 0.f, 0.f, 0.f};
    floatx4 a1 = {0.f, 0.f, 0.f, 0.f};
    const int nrow = wave * 16 + l16;
#pragma unroll
    for (int ks = 0; ks < 4; ks++) {
      bf16x8 b = *(const bf16x8*)&kvbuf[nrow * KS_STRIDE + ks * 32 + quad * 8];
      a0 = __builtin_amdgcn_mfma_f32_16x16x32_bf16(afrag[0][ks], b, a0, 0, 0, 0);
      a1 = __builtin_amdgcn_mfma_f32_16x16x32_bf16(afrag[1][ks], b, a1, 0, 0, 0);
    }
    sc[c][0] = a0;
    sc[c][1] = a1;
    __syncthreads();  // kvbuf read done
    if (c < 3) {      // gather next K chunk
      int r = tid >> 2, seg = tid & 3;
      int idx = topk_s[(c + 1) * 64 + r];
      const float* kp = kv + (size_t)idx * (2 * DH);
      int d0 = seg * 32;
      unsigned short* dst = &kvbuf[r * KS_STRIDE];
#pragma unroll
      for (int i = 0; i < 8; i++) {
        float4 f = *(const float4*)(kp + d0 + i * 4);
        ushort4_t u = { f2bf(f.x), f2bf(f.y), f2bf(f.z), f2bf(f.w) };
        *(ushort4_t*)&dst[d0 + i * 4] = u;
      }
      __syncthreads();  // kvbuf write visible
    }
  }

  // ---- V chunk 0 gather: overlaps with softmax below ----
  {
    int r = tid & 63, dq = tid >> 6;
    int idx = topk_s[r];
    const float* vp = kv + (size_t)idx * (2 * DH) + DH;
    int d0 = dq * 32;
#pragma unroll
    for (int i = 0; i < 8; i++) {
      float4 f = *(const float4*)(vp + d0 + i * 4);
      int d = d0 + i * 4;
      kvbuf[(d + 0) * VB_STRIDE + r] = f2bf(f.x);
      kvbuf[(d + 1) * VB_STRIDE + r] = f2bf(f.y);
      kvbuf[(d + 2) * VB_STRIDE + r] = f2bf(f.z);
      kvbuf[(d + 3) * VB_STRIDE + r] = f2bf(f.w);
    }
  }

  // ---- Phase 2: in-register softmax with sink ----
  // head h = mt*16 + quad*4 + r ; col = c*64 + wave*16 + l16
  float mh[2][4];
#pragma unroll
  for (int mt = 0; mt < 2; mt++)
#pragma unroll
    for (int r = 0; r < 4; r++)
      mh[mt][r] = fmaxf(fmaxf(sc[0][mt][r], sc[1][mt][r]),
                        fmaxf(sc[2][mt][r], sc[3][mt][r]));
#pragma unroll
  for (int off = 1; off < 16; off <<= 1)
#pragma unroll
    for (int mt = 0; mt < 2; mt++)
#pragma unroll
      for (int r = 0; r < 4; r++)
        mh[mt][r] = fmaxf(mh[mt][r], __shfl_xor(mh[mt][r], off));
  if (l16 == 0) {
#pragma unroll
    for (int mt = 0; mt < 2; mt++)
#pragma unroll
      for (int r = 0; r < 4; r++)
        red[wave * 32 + mt * 16 + quad * 4 + r] = mh[mt][r];
  }
  __syncthreads();
#pragma unroll
  for (int mt = 0; mt < 2; mt++)
#pragma unroll
    for (int r = 0; r < 4; r++) {
      int h = mt * 16 + quad * 4 + r;
      float v = sink_s[h];
#pragma unroll
      for (int w = 0; w < 4; w++) v = fmaxf(v, red[w * 32 + h]);
      mh[mt][r] = v;
    }
  float ps[2][4] = {{0.f, 0.f, 0.f, 0.f}, {0.f, 0.f, 0.f, 0.f}};
#pragma unroll
  for (int c = 0; c < 4; c++)
#pragma unroll
    for (int mt = 0; mt < 2; mt++)
#pragma unroll
      for (int r = 0; r < 4; r++) {
        float e = __expf(sc[c][mt][r] - mh[mt][r]);
        sc[c][mt][r] = e;
        ps[mt][r] += e;
      }
#pragma unroll
  for (int off = 1; off < 16; off <<= 1)
#pragma unroll
    for (int mt = 0; mt < 2; mt++)
#pragma unroll
      for (int r = 0; r < 4; r++)
        ps[mt][r] += __shfl_xor(ps[mt][r], off);
  if (l16 == 0) {
#pragma unroll
    for (int mt = 0; mt < 2; mt++)
#pragma unroll
      for (int r = 0; r < 4; r++)
        red2[wave * 32 + mt * 16 + quad * 4 + r] = ps[mt][r];
  }
  __syncthreads();
  float inv[2][4];
#pragma unroll
  for (int mt = 0; mt < 2; mt++)
#pragma unroll
    for (int r = 0; r < 4; r++) {
      int h = mt * 16 + quad * 4 + r;
      float dd = __expf(sink_s[h] - mh[mt][r]);
#pragma unroll
      for (int w = 0; w < 4; w++) dd += red2[w * 32 + h];
      inv[mt][r] = 1.0f / dd;
    }
  // write P (bf16, unnormalized) to pbuf in [head][col] layout
#pragma unroll
  for (int c = 0; c < 4; c++)
#pragma unroll
    for (int mt = 0; mt < 2; mt++)
#pragma unroll
      for (int r = 0; r < 4; r++)
        pbuf[(mt * 16 + quad * 4 + r) * PB_STRIDE + c * 64 + wave * 16 + l16] =
            f2bf(sc[c][mt][r]);
  __syncthreads();  // pbuf + V chunk 0 visible

  // ---- Phase 3: O = P V_g ----
  floatx4 oacc[2][2];
#pragma unroll
  for (int mt = 0; mt < 2; mt++)
#pragma unroll
    for (int nt = 0; nt < 2; nt++)
      oacc[mt][nt] = (floatx4){0.f, 0.f, 0.f, 0.f};

#pragma unroll 1
  for (int c = 0; c < 4; c++) {
#pragma unroll
    for (int ks = 0; ks < 2; ks++) {
      int kof = c * 64 + ks * 32 + quad * 8;
      bf16x8 a0 = *(const bf16x8*)&pbuf[l16 * PB_STRIDE + kof];
      bf16x8 a1 = *(const bf16x8*)&pbuf[(16 + l16) * PB_STRIDE + kof];
      int kl = ks * 32 + quad * 8;
      bf16x8 b0 = *(const bf16x8*)&kvbuf[(wave * 32 + l16) * VB_STRIDE + kl];
      bf16x8 b1 = *(const bf16x8*)&kvbuf[(wave * 32 + 16 + l16) * VB_STRIDE + kl];
      oacc[0][0] = __builtin_amdgcn_mfma_f32_16x16x32_bf16(a0, b0, oacc[0][0], 0, 0, 0);
      oacc[0][1] = __builtin_amdgcn_mfma_f32_16x16x32_bf16(a0, b1, oacc[0][1], 0, 0, 0);
      oacc[1][0] = __builtin_amdgcn_mfma_f32_16x16x32_bf16(a1, b0, oacc[1][0], 0, 0, 0);
      oacc[1][1] = __builtin_amdgcn_mfma_f32_16x16x32_bf16(a1, b1, oacc[1][1], 0, 0, 0);
    }
    if (c < 3) {
      __syncthreads();  // kvbuf read done
      int r = tid & 63, dq = tid >> 6;
      int idx = topk_s[(c + 1) * 64 + r];
      const float* vp = kv + (size_t)idx * (2 * DH) + DH;
      int d0 = dq * 32;
#pragma unroll
      for (int i = 0; i < 8; i++) {
        float4 f = *(const float4*)(vp + d0 + i * 4);
        int d = d0 + i * 4;
        kvbuf[(d + 0) * VB_STRIDE + r] = f2bf(f.x);
        kvbuf[(d + 1) * VB_STRIDE + r] = f2bf(f.y);
        kvbuf[(d + 2) * VB_STRIDE + r] = f2bf(f.z);
        kvbuf[(d + 3) * VB_STRIDE + r] = f2bf(f.w);
      }
      __syncthreads();  // kvbuf write visible
    }
  }

  // ---- Phase 4: epilogue ----
  {
    float* op = out + (size_t)s * (NH * DH);
#pragma unroll
    for (int mt = 0; mt < 2; mt++)
#pragma unroll
      for (int nt = 0; nt < 2; nt++)
#pragma unroll
        for (int r4 = 0; r4 < 4; r4++) {
          int h = mt * 16 + quad * 4 + r4;
          int d = wave * 32 + nt * 16 + l16;
          op[h * DH + d] = oacc[mt][nt][r4] * inv[mt][r4];
        }
  }
}

extern "C" void kernel_launch(void* const* d_in, const int* in_sizes, int n_in,
                              void* d_out, int out_size, void* d_ws, size_t ws_size,
                              hipStream_t stream) {
  (void)in_sizes; (void)n_in; (void)out_size; (void)d_ws; (void)ws_size;
  const float* q    = (const float*)d_in[0];
  const float* kv   = (const float*)d_in[1];
  const float* sink = (const float*)d_in[2];
  const int*   topk = (const int*)d_in[3];
  float* out = (float*)d_out;
  sparse_attn_kernel<<<dim3(SQ), dim3(256), 0, stream>>>(q, kv, sink, topk, out);
}

// Round 3
// 117.515 us; speedup vs baseline: 1.4356x; 1.3023x over previous
//
#include <hip/hip_runtime.h>
#include <hip/hip_bf16.h>

#define SQ 2048
#define NH 32
#define DH 128
#define NK 256
#define SCALE 0.08838834764831845f

typedef __attribute__((ext_vector_type(8))) __bf16 bf16x8;
typedef __attribute__((ext_vector_type(4))) float floatx4;
typedef __attribute__((ext_vector_type(4))) unsigned short ushort4_t;

// element strides (u16)
#define QS_STRIDE 136   // 272 B rows: 16B-aligned b128 frags, 2-way-max banks (free)
#define KS_STRIDE 136
#define VB_STRIDE 72    // V transposed [d][k_local]; 144 B rows (16B-aligned)
#define PB_STRIDE 264

// LDS layout (bytes), total 37504 -> 4 blocks/CU
#define OFF_KV   16896
#define OFF_TOPK 35328
#define OFF_SINK 36352
#define OFF_RED  36480
#define OFF_RED2 36992
#define SMEM_SZ  37504

__device__ __forceinline__ unsigned short f2bf(float x) {
  union { float f; unsigned int u; } v; v.f = x;
  unsigned int r = v.u + 0x7FFFu + ((v.u >> 16) & 1u);
  return (unsigned short)(r >> 16);
}

// rotate-by-N within each row of 16 lanes (VALU DPP, keeps reductions off LDS pipe)
template <int CTRL>
__device__ __forceinline__ float dpp_rot(float x) {
  int i = __builtin_bit_cast(int, x);
  i = __builtin_amdgcn_mov_dpp(i, CTRL, 0xF, 0xF, true);
  return __builtin_bit_cast(float, i);
}
#define RED16_MAX(v) { v = fmaxf(v, dpp_rot<0x121>(v)); v = fmaxf(v, dpp_rot<0x122>(v)); \
                       v = fmaxf(v, dpp_rot<0x124>(v)); v = fmaxf(v, dpp_rot<0x128>(v)); }
#define RED16_SUM(v) { v += dpp_rot<0x121>(v); v += dpp_rot<0x122>(v); \
                       v += dpp_rot<0x124>(v); v += dpp_rot<0x128>(v); }

// ---- pre-pass: kv fp32 [4096][2][128] -> bf16 in d_ws (same layout) ----
__global__ __launch_bounds__(256) void kv_to_bf16(const float* __restrict__ kv,
                                                  unsigned short* __restrict__ kvb) {
  int i = blockIdx.x * 256 + threadIdx.x;  // float4 index; grid covers 1M elems exactly
  float4 f = ((const float4*)kv)[i];
  ushort4_t u = { f2bf(f.x), f2bf(f.y), f2bf(f.z), f2bf(f.w) };
  ((ushort4_t*)kvb)[i] = u;
}

__global__ __launch_bounds__(256, 4) void sparse_attn_kernel(
    const float* __restrict__ q, const unsigned short* __restrict__ kvb,
    const float* __restrict__ sink, const int* __restrict__ topk,
    float* __restrict__ out) {
  __shared__ __align__(16) char smem[SMEM_SZ];
  unsigned short* qs    = (unsigned short*)smem;            // phase 0 only
  unsigned short* pbuf  = (unsigned short*)smem;            // softmax onward
  unsigned short* kvbuf = (unsigned short*)(smem + OFF_KV); // K chunk / V^T chunk
  int*   topk_s = (int*)(smem + OFF_TOPK);
  float* sink_s = (float*)(smem + OFF_SINK);
  float* red    = (float*)(smem + OFF_RED);
  float* red2   = (float*)(smem + OFF_RED2);

  const int tid = threadIdx.x;
  const int s = blockIdx.x;
  const int wave = tid >> 6;
  const int lane = tid & 63;
  const int quad = lane >> 4;
  const int l16 = lane & 15;

  // ---- Phase 0: topk+sink -> LDS, K chunk 0 gather (bf16 copy), Q -> LDS ----
  topk_s[tid] = topk[(size_t)s * NK + tid];
  if (tid < 32) sink_s[tid] = sink[tid];
  {  // K chunk 0: pure b128 copy, no conversion
    int r = tid >> 2, seg = tid & 3;
    int idx = topk[(size_t)s * NK + r];
    const unsigned short* kp = kvb + (size_t)idx * 256 + seg * 32;
    unsigned short* dst = &kvbuf[r * KS_STRIDE + seg * 32];
#pragma unroll
    for (int i = 0; i < 4; i++)
      *(uint4*)&dst[i * 8] = *(const uint4*)&kp[i * 8];
  }
  {  // Q stage (pre-scaled bf16)
    const float* qp = q + (size_t)s * (NH * DH);
    int h = tid >> 3;
    int d0 = (tid & 7) * 16;
#pragma unroll
    for (int i = 0; i < 4; i++) {
      float4 f = *(const float4*)(qp + h * DH + d0 + i * 4);
      ushort4_t u = { f2bf(f.x * SCALE), f2bf(f.y * SCALE),
                      f2bf(f.z * SCALE), f2bf(f.w * SCALE) };
      *(ushort4_t*)&qs[h * QS_STRIDE + d0 + i * 4] = u;
    }
  }
  __syncthreads();

  // Hoist Q A-fragments: A[m=l16][k=quad*8+j]; qs dead afterwards
  bf16x8 afrag[2][4];
#pragma unroll
  for (int mt = 0; mt < 2; mt++)
#pragma unroll
    for (int ks = 0; ks < 4; ks++)
      afrag[mt][ks] =
          *(const bf16x8*)&qs[(mt * 16 + l16) * QS_STRIDE + ks * 32 + quad * 8];

  // ---- Phase 1: GEMM1, scores kept in registers (C-layout) ----
  floatx4 sc[4][2];
#pragma unroll 1
  for (int c = 0; c < 4; c++) {
    floatx4 a0 = {0.f, 0.f, 0.f, 0.f};
    floatx4 a1 = {0.f, 0.f, 0.f, 0.f};
    const int nrow = wave * 16 + l16;
#pragma unroll
    for (int ks = 0; ks < 4; ks++) {
      bf16x8 b = *(const bf16x8*)&kvbuf[nrow * KS_STRIDE + ks * 32 + quad * 8];
      a0 = __builtin_amdgcn_mfma_f32_16x16x32_bf16(afrag[0][ks], b, a0, 0, 0, 0);
      a1 = __builtin_amdgcn_mfma_f32_16x16x32_bf16(afrag[1][ks], b, a1, 0, 0, 0);
    }
    sc[c][0] = a0;
    sc[c][1] = a1;
    __syncthreads();  // kvbuf reads done
    if (c < 3) {      // gather next K chunk (b128 copy)
      int r = tid >> 2, seg = tid & 3;
      int idx = topk_s[(c + 1) * 64 + r];
      const unsigned short* kp = kvb + (size_t)idx * 256 + seg * 32;
      unsigned short* dst = &kvbuf[r * KS_STRIDE + seg * 32];
#pragma unroll
      for (int i = 0; i < 4; i++)
        *(uint4*)&dst[i * 8] = *(const uint4*)&kp[i * 8];
      __syncthreads();  // kvbuf writes visible
    }
  }

  // ---- V chunk 0 gather (transposed via v_perm packing), overlaps softmax ----
  // thread: 4 rows (r0=rg*4) x 8 d (d0=dg*8); writes b64 along k_local
  {
    int rg = tid & 15, dg = tid >> 4;
    int r0 = rg * 4, d0 = dg * 8;
    int4 idx4 = *(const int4*)&topk_s[r0];
    uint4 ra = *(const uint4*)(kvb + (size_t)idx4.x * 256 + 128 + d0);
    uint4 rb = *(const uint4*)(kvb + (size_t)idx4.y * 256 + 128 + d0);
    uint4 rc = *(const uint4*)(kvb + (size_t)idx4.z * 256 + 128 + d0);
    uint4 rd = *(const uint4*)(kvb + (size_t)idx4.w * 256 + 128 + d0);
    const unsigned* pa = (const unsigned*)&ra;
    const unsigned* pb = (const unsigned*)&rb;
    const unsigned* pc = (const unsigned*)&rc;
    const unsigned* pd = (const unsigned*)&rd;
#pragma unroll
    for (int w = 0; w < 4; w++) {
      unsigned lo01 = __builtin_amdgcn_perm(pb[w], pa[w], 0x05040100u);
      unsigned lo23 = __builtin_amdgcn_perm(pd[w], pc[w], 0x05040100u);
      unsigned hi01 = __builtin_amdgcn_perm(pb[w], pa[w], 0x07060302u);
      unsigned hi23 = __builtin_amdgcn_perm(pd[w], pc[w], 0x07060302u);
      uint2 lo = { lo01, lo23 }, hi = { hi01, hi23 };
      *(uint2*)&kvbuf[(d0 + 2 * w) * VB_STRIDE + r0] = lo;
      *(uint2*)&kvbuf[(d0 + 2 * w + 1) * VB_STRIDE + r0] = hi;
    }
  }

  // ---- Phase 2: softmax with sink (DPP rotate-reduce, VALU pipe) ----
  float mh[2][4];
#pragma unroll
  for (int mt = 0; mt < 2; mt++)
#pragma unroll
    for (int r = 0; r < 4; r++) {
      float v = fmaxf(fmaxf(sc[0][mt][r], sc[1][mt][r]),
                      fmaxf(sc[2][mt][r], sc[3][mt][r]));
      RED16_MAX(v);
      mh[mt][r] = v;
    }
  if (l16 == 0) {
#pragma unroll
    for (int mt = 0; mt < 2; mt++)
#pragma unroll
      for (int r = 0; r < 4; r++)
        red[wave * 32 + mt * 16 + quad * 4 + r] = mh[mt][r];
  }
  __syncthreads();
#pragma unroll
  for (int mt = 0; mt < 2; mt++)
#pragma unroll
    for (int r = 0; r < 4; r++) {
      int h = mt * 16 + quad * 4 + r;
      float v = sink_s[h];
#pragma unroll
      for (int w = 0; w < 4; w++) v = fmaxf(v, red[w * 32 + h]);
      mh[mt][r] = v;
    }
  float ps[2][4];
#pragma unroll
  for (int mt = 0; mt < 2; mt++)
#pragma unroll
    for (int r = 0; r < 4; r++) {
      float acc = 0.f;
#pragma unroll
      for (int c = 0; c < 4; c++) {
        float e = __expf(sc[c][mt][r] - mh[mt][r]);
        sc[c][mt][r] = e;
        acc += e;
      }
      RED16_SUM(acc);
      ps[mt][r] = acc;
    }
  if (l16 == 0) {
#pragma unroll
    for (int mt = 0; mt < 2; mt++)
#pragma unroll
      for (int r = 0; r < 4; r++)
        red2[wave * 32 + mt * 16 + quad * 4 + r] = ps[mt][r];
  }
  __syncthreads();
  float inv[2][4];
#pragma unroll
  for (int mt = 0; mt < 2; mt++)
#pragma unroll
    for (int r = 0; r < 4; r++) {
      int h = mt * 16 + quad * 4 + r;
      float dd = __expf(sink_s[h] - mh[mt][r]);
#pragma unroll
      for (int w = 0; w < 4; w++) dd += red2[w * 32 + h];
      inv[mt][r] = 1.0f / dd;
    }
  // write P (bf16, unnormalized) to pbuf [head][col]
#pragma unroll
  for (int c = 0; c < 4; c++)
#pragma unroll
    for (int mt = 0; mt < 2; mt++)
#pragma unroll
      for (int r = 0; r < 4; r++)
        pbuf[(mt * 16 + quad * 4 + r) * PB_STRIDE + c * 64 + wave * 16 + l16] =
            f2bf(sc[c][mt][r]);
  __syncthreads();  // pbuf + V chunk 0 visible

  // ---- Phase 3: O = P V_g ----
  floatx4 oacc[2][2];
#pragma unroll
  for (int mt = 0; mt < 2; mt++)
#pragma unroll
    for (int nt = 0; nt < 2; nt++)
      oacc[mt][nt] = (floatx4){0.f, 0.f, 0.f, 0.f};

#pragma unroll 1
  for (int c = 0; c < 4; c++) {
#pragma unroll
    for (int ks = 0; ks < 2; ks++) {
      int kof = c * 64 + ks * 32 + quad * 8;
      bf16x8 a0 = *(const bf16x8*)&pbuf[l16 * PB_STRIDE + kof];
      bf16x8 a1 = *(const bf16x8*)&pbuf[(16 + l16) * PB_STRIDE + kof];
      int kl = ks * 32 + quad * 8;
      bf16x8 b0 = *(const bf16x8*)&kvbuf[(wave * 32 + l16) * VB_STRIDE + kl];
      bf16x8 b1 = *(const bf16x8*)&kvbuf[(wave * 32 + 16 + l16) * VB_STRIDE + kl];
      oacc[0][0] = __builtin_amdgcn_mfma_f32_16x16x32_bf16(a0, b0, oacc[0][0], 0, 0, 0);
      oacc[0][1] = __builtin_amdgcn_mfma_f32_16x16x32_bf16(a0, b1, oacc[0][1], 0, 0, 0);
      oacc[1][0] = __builtin_amdgcn_mfma_f32_16x16x32_bf16(a1, b0, oacc[1][0], 0, 0, 0);
      oacc[1][1] = __builtin_amdgcn_mfma_f32_16x16x32_bf16(a1, b1, oacc[1][1], 0, 0, 0);
    }
    if (c < 3) {
      __syncthreads();  // kvbuf reads done
      int rg = tid & 15, dg = tid >> 4;
      int r0 = rg * 4, d0 = dg * 8;
      int4 idx4 = *(const int4*)&topk_s[(c + 1) * 64 + r0];
      uint4 ra = *(const uint4*)(kvb + (size_t)idx4.x * 256 + 128 + d0);
      uint4 rb = *(const uint4*)(kvb + (size_t)idx4.y * 256 + 128 + d0);
      uint4 rc = *(const uint4*)(kvb + (size_t)idx4.z * 256 + 128 + d0);
      uint4 rd = *(const uint4*)(kvb + (size_t)idx4.w * 256 + 128 + d0);
      const unsigned* pa = (const unsigned*)&ra;
      const unsigned* pb = (const unsigned*)&rb;
      const unsigned* pc = (const unsigned*)&rc;
      const unsigned* pd = (const unsigned*)&rd;
#pragma unroll
      for (int w = 0; w < 4; w++) {
        unsigned lo01 = __builtin_amdgcn_perm(pb[w], pa[w], 0x05040100u);
        unsigned lo23 = __builtin_amdgcn_perm(pd[w], pc[w], 0x05040100u);
        unsigned hi01 = __builtin_amdgcn_perm(pb[w], pa[w], 0x07060302u);
        unsigned hi23 = __builtin_amdgcn_perm(pd[w], pc[w], 0x07060302u);
        uint2 lo = { lo01, lo23 }, hi = { hi01, hi23 };
        *(uint2*)&kvbuf[(d0 + 2 * w) * VB_STRIDE + r0] = lo;
        *(uint2*)&kvbuf[(d0 + 2 * w + 1) * VB_STRIDE + r0] = hi;
      }
      __syncthreads();  // kvbuf writes visible
    }
  }

  // ---- Phase 4: epilogue ----
  {
    float* op = out + (size_t)s * (NH * DH);
#pragma unroll
    for (int mt = 0; mt < 2; mt++)
#pragma unroll
      for (int nt = 0; nt < 2; nt++)
#pragma unroll
        for (int r4 = 0; r4 < 4; r4++) {
          int h = mt * 16 + quad * 4 + r4;
          int d = wave * 32 + nt * 16 + l16;
          op[h * DH + d] = oacc[mt][nt][r4] * inv[mt][r4];
        }
  }
}

extern "C" void kernel_launch(void* const* d_in, const int* in_sizes, int n_in,
                              void* d_out, int out_size, void* d_ws, size_t ws_size,
                              hipStream_t stream) {
  (void)in_sizes; (void)n_in; (void)out_size; (void)ws_size;
  const float* q    = (const float*)d_in[0];
  const float* kv   = (const float*)d_in[1];
  const float* sink = (const float*)d_in[2];
  const int*   topk = (const int*)d_in[3];
  float* out = (float*)d_out;
  unsigned short* kvb = (unsigned short*)d_ws;  // 2 MB bf16 KV

  kv_to_bf16<<<dim3(1024), dim3(256), 0, stream>>>(kv, kvb);
  sparse_attn_kernel<<<dim3(SQ), dim3(256), 0, stream>>>(q, kvb, sink, topk, out);
}

// Round 4
// 113.372 us; speedup vs baseline: 1.4881x; 1.0365x over previous
//
#include <hip/hip_runtime.h>
#include <hip/hip_bf16.h>

#define SQ 2048
#define NH 32
#define DH 128
#define NK 256
#define SCALE 0.08838834764831845f
#define LOG2E 1.4426950408889634f

typedef __attribute__((ext_vector_type(8))) __bf16 bf16x8;
typedef __attribute__((ext_vector_type(4))) float floatx4;

// element strides (u16)
#define QS_STRIDE 136   // 272 B rows: 16B-aligned b128 frags, 2-way banks (free)
#define KS_STRIDE 136
#define VB_STRIDE 72    // V transposed [d][k_local]; 144 B rows
#define PB_STRIDE 264

// LDS layout (bytes), total 37504 -> 4 blocks/CU
#define OFF_KV   16896
#define OFF_TOPK 35328
#define OFF_SINK 36352
#define OFF_RED  36480
#define OFF_RED2 36992
#define SMEM_SZ  37504

__device__ __forceinline__ unsigned pk_bf16(float a, float b) {
  // v_cvt_pk_bf16_f32 (RNE), packs two fp32 -> one dword of 2 bf16
  union { __hip_bfloat162 h2; unsigned u; } c;
  c.h2 = __float22bfloat162_rn(make_float2(a, b));
  return c.u;
}

__device__ __forceinline__ float fast_exp2(float x) {
#if __has_builtin(__builtin_amdgcn_exp2f)
  return __builtin_amdgcn_exp2f(x);
#else
  return exp2f(x);
#endif
}

// rotate within rows of 16 lanes (VALU DPP — keeps reductions off the LDS pipe)
template <int CTRL>
__device__ __forceinline__ float dpp_rot(float x) {
  int i = __builtin_bit_cast(int, x);
  i = __builtin_amdgcn_mov_dpp(i, CTRL, 0xF, 0xF, true);
  return __builtin_bit_cast(float, i);
}
#define RED16_MAX(v) { v = fmaxf(v, dpp_rot<0x121>(v)); v = fmaxf(v, dpp_rot<0x122>(v)); \
                       v = fmaxf(v, dpp_rot<0x124>(v)); v = fmaxf(v, dpp_rot<0x128>(v)); }
#define RED16_SUM(v) { v += dpp_rot<0x121>(v); v += dpp_rot<0x122>(v); \
                       v += dpp_rot<0x124>(v); v += dpp_rot<0x128>(v); }

// ---- pre-pass: kv fp32 [4096][2][128] -> bf16 in d_ws ----
__global__ __launch_bounds__(256) void kv_to_bf16(const float* __restrict__ kv,
                                                  unsigned short* __restrict__ kvb) {
  int i = blockIdx.x * 256 + threadIdx.x;  // float4 index, 262144 total
  float4 f = ((const float4*)kv)[i];
  uint2 o = { pk_bf16(f.x, f.y), pk_bf16(f.z, f.w) };
  ((uint2*)kvb)[i] = o;
}

struct KR { uint4 v[4]; };
struct VR { uint4 a, b, c, d; };

__device__ __forceinline__ KR k_load(const unsigned short* __restrict__ kvb,
                                     const int* __restrict__ tks, int c, int tid) {
  int r = tid >> 2, seg = tid & 3;
  int idx = tks[c * 64 + r];
  const uint4* p = (const uint4*)(kvb + (size_t)idx * 256 + seg * 32);
  KR k;
#pragma unroll
  for (int i = 0; i < 4; i++) k.v[i] = p[i];
  return k;
}

__device__ __forceinline__ void k_write(unsigned short* kvbuf, const KR& k, int tid) {
  int r = tid >> 2, seg = tid & 3;
  uint4* d = (uint4*)&kvbuf[r * KS_STRIDE + seg * 32];
#pragma unroll
  for (int i = 0; i < 4; i++) d[i] = k.v[i];
}

__device__ __forceinline__ VR v_load(const unsigned short* __restrict__ kvb,
                                     const int* tks, int c, int tid) {
  int rg = tid & 15, dg = tid >> 4;
  int r0 = rg * 4, d0 = dg * 8;
  int4 i4 = *(const int4*)&tks[c * 64 + r0];
  VR v;
  v.a = *(const uint4*)(kvb + (size_t)i4.x * 256 + 128 + d0);
  v.b = *(const uint4*)(kvb + (size_t)i4.y * 256 + 128 + d0);
  v.c = *(const uint4*)(kvb + (size_t)i4.z * 256 + 128 + d0);
  v.d = *(const uint4*)(kvb + (size_t)i4.w * 256 + 128 + d0);
  return v;
}

__device__ __forceinline__ void v_write(unsigned short* kvbuf, const VR& v, int tid) {
  int rg = tid & 15, dg = tid >> 4;
  int r0 = rg * 4, d0 = dg * 8;
  const unsigned* pa = (const unsigned*)&v.a;
  const unsigned* pb = (const unsigned*)&v.b;
  const unsigned* pc = (const unsigned*)&v.c;
  const unsigned* pd = (const unsigned*)&v.d;
#pragma unroll
  for (int w = 0; w < 4; w++) {
    unsigned lo01 = __builtin_amdgcn_perm(pb[w], pa[w], 0x05040100u);
    unsigned lo23 = __builtin_amdgcn_perm(pd[w], pc[w], 0x05040100u);
    unsigned hi01 = __builtin_amdgcn_perm(pb[w], pa[w], 0x07060302u);
    unsigned hi23 = __builtin_amdgcn_perm(pd[w], pc[w], 0x07060302u);
    uint2 lo = { lo01, lo23 }, hi = { hi01, hi23 };
    *(uint2*)&kvbuf[(d0 + 2 * w) * VB_STRIDE + r0] = lo;
    *(uint2*)&kvbuf[(d0 + 2 * w + 1) * VB_STRIDE + r0] = hi;
  }
}

__device__ __forceinline__ void gemm1(const unsigned short* kvbuf,
                                      const bf16x8 af[2][4], int nrow, int quad,
                                      floatx4& a0, floatx4& a1) {
  a0 = (floatx4){0.f, 0.f, 0.f, 0.f};
  a1 = (floatx4){0.f, 0.f, 0.f, 0.f};
#pragma unroll
  for (int ks = 0; ks < 4; ks++) {
    bf16x8 b = *(const bf16x8*)&kvbuf[nrow * KS_STRIDE + ks * 32 + quad * 8];
    a0 = __builtin_amdgcn_mfma_f32_16x16x32_bf16(af[0][ks], b, a0, 0, 0, 0);
    a1 = __builtin_amdgcn_mfma_f32_16x16x32_bf16(af[1][ks], b, a1, 0, 0, 0);
  }
}

__device__ __forceinline__ void pv_chunk(const unsigned short* pbuf,
                                         const unsigned short* kvbuf, int c,
                                         int wave, int quad, int l16,
                                         floatx4 oacc[2][2]) {
#pragma unroll
  for (int ks = 0; ks < 2; ks++) {
    int kof = c * 64 + ks * 32 + quad * 8;
    bf16x8 a0 = *(const bf16x8*)&pbuf[l16 * PB_STRIDE + kof];
    bf16x8 a1 = *(const bf16x8*)&pbuf[(16 + l16) * PB_STRIDE + kof];
    int kl = ks * 32 + quad * 8;
    bf16x8 b0 = *(const bf16x8*)&kvbuf[(wave * 32 + l16) * VB_STRIDE + kl];
    bf16x8 b1 = *(const bf16x8*)&kvbuf[(wave * 32 + 16 + l16) * VB_STRIDE + kl];
    oacc[0][0] = __builtin_amdgcn_mfma_f32_16x16x32_bf16(a0, b0, oacc[0][0], 0, 0, 0);
    oacc[0][1] = __builtin_amdgcn_mfma_f32_16x16x32_bf16(a0, b1, oacc[0][1], 0, 0, 0);
    oacc[1][0] = __builtin_amdgcn_mfma_f32_16x16x32_bf16(a1, b0, oacc[1][0], 0, 0, 0);
    oacc[1][1] = __builtin_amdgcn_mfma_f32_16x16x32_bf16(a1, b1, oacc[1][1], 0, 0, 0);
  }
}

__global__ __launch_bounds__(256, 4) void sparse_attn_kernel(
    const float* __restrict__ q, const unsigned short* __restrict__ kvb,
    const float* __restrict__ sink, const int* __restrict__ topk,
    float* __restrict__ out) {
  __shared__ __align__(16) char smem[SMEM_SZ];
  unsigned short* qs    = (unsigned short*)smem;            // phase 0 only
  unsigned short* pbuf  = (unsigned short*)smem;            // softmax onward
  unsigned short* kvbuf = (unsigned short*)(smem + OFF_KV); // K chunk / V^T chunk
  int*   topk_s = (int*)(smem + OFF_TOPK);
  float* sink_s = (float*)(smem + OFF_SINK);
  float* red    = (float*)(smem + OFF_RED);
  float* red2   = (float*)(smem + OFF_RED2);

  const int tid = threadIdx.x;
  const int s = blockIdx.x;
  const int wave = tid >> 6;
  const int lane = tid & 63;
  const int quad = lane >> 4;
  const int l16 = lane & 15;
  const int* tkg = topk + (size_t)s * NK;

  // ---- Phase 0: topk+sink -> LDS; K0 direct to LDS; Q staged (scaled) ----
  topk_s[tid] = tkg[tid];
  if (tid < 32) sink_s[tid] = sink[tid] * LOG2E;
  {  // K chunk 0: straight b128 copy
    int r = tid >> 2, seg = tid & 3;
    int idx = tkg[r];
    const uint4* p = (const uint4*)(kvb + (size_t)idx * 256 + seg * 32);
    uint4* d = (uint4*)&kvbuf[r * KS_STRIDE + seg * 32];
#pragma unroll
    for (int i = 0; i < 4; i++) d[i] = p[i];
  }
  {  // Q stage, pre-scaled by SCALE*log2(e) so softmax uses raw exp2
    const float QSC = SCALE * LOG2E;
    const float* qp = q + (size_t)s * (NH * DH);
    int h = tid >> 3, d0 = (tid & 7) * 16;
    const float4* src = (const float4*)(qp + h * DH + d0);
    float4 f0 = src[0], f1 = src[1], f2 = src[2], f3 = src[3];
    uint4 o0 = { pk_bf16(f0.x * QSC, f0.y * QSC), pk_bf16(f0.z * QSC, f0.w * QSC),
                 pk_bf16(f1.x * QSC, f1.y * QSC), pk_bf16(f1.z * QSC, f1.w * QSC) };
    uint4 o1 = { pk_bf16(f2.x * QSC, f2.y * QSC), pk_bf16(f2.z * QSC, f2.w * QSC),
                 pk_bf16(f3.x * QSC, f3.y * QSC), pk_bf16(f3.z * QSC, f3.w * QSC) };
    *(uint4*)&qs[h * QS_STRIDE + d0] = o0;
    *(uint4*)&qs[h * QS_STRIDE + d0 + 8] = o1;
  }
  KR k1 = k_load(kvb, tkg, 1, tid);  // prefetch K1 (regs) during phase 0
  __syncthreads();

  // Hoist Q A-fragments: A[m=l16][k=quad*8+j]; qs dead afterwards
  bf16x8 afrag[2][4];
#pragma unroll
  for (int mt = 0; mt < 2; mt++)
#pragma unroll
    for (int ks = 0; ks < 4; ks++)
      afrag[mt][ks] =
          *(const bf16x8*)&qs[(mt * 16 + l16) * QS_STRIDE + ks * 32 + quad * 8];

  const int nrow = wave * 16 + l16;

  // ---- Phase 1: GEMM1 with register-prefetch pipeline ----
  floatx4 sc[4][2];
  gemm1(kvbuf, afrag, nrow, quad, sc[0][0], sc[0][1]);
  __syncthreads();                 // K0 reads done
  k_write(kvbuf, k1, tid);         // cheap VGPR->LDS
  KR k2 = k_load(kvb, topk_s, 2, tid);  // prefetch K2 (overlaps gemm c1)
  __syncthreads();                 // K1 visible

  gemm1(kvbuf, afrag, nrow, quad, sc[1][0], sc[1][1]);
  __syncthreads();
  k_write(kvbuf, k2, tid);
  KR k3 = k_load(kvb, topk_s, 3, tid);
  __syncthreads();

  gemm1(kvbuf, afrag, nrow, quad, sc[2][0], sc[2][1]);
  __syncthreads();
  k_write(kvbuf, k3, tid);
  VR v0 = v_load(kvb, topk_s, 0, tid);  // prefetch V0 (overlaps gemm c3)
  __syncthreads();

  gemm1(kvbuf, afrag, nrow, quad, sc[3][0], sc[3][1]);
  __syncthreads();                 // K3 reads done
  v_write(kvbuf, v0, tid);         // V0 -> LDS transposed
  VR v1 = v_load(kvb, topk_s, 1, tid);  // prefetch V1 (overlaps softmax)

  // ---- Phase 2: softmax with sink (scores are in exp2 domain) ----
  float mh[2][4];
#pragma unroll
  for (int mt = 0; mt < 2; mt++)
#pragma unroll
    for (int r = 0; r < 4; r++) {
      float v = fmaxf(fmaxf(sc[0][mt][r], sc[1][mt][r]),
                      fmaxf(sc[2][mt][r], sc[3][mt][r]));
      RED16_MAX(v);
      mh[mt][r] = v;
    }
  if (l16 == 0) {
#pragma unroll
    for (int mt = 0; mt < 2; mt++)
#pragma unroll
      for (int r = 0; r < 4; r++)
        red[wave * 32 + mt * 16 + quad * 4 + r] = mh[mt][r];
  }
  __syncthreads();  // red visible (also covers V0 writes; pbuf barrier below re-covers)
#pragma unroll
  for (int mt = 0; mt < 2; mt++)
#pragma unroll
    for (int r = 0; r < 4; r++) {
      int h = mt * 16 + quad * 4 + r;
      float v = sink_s[h];
#pragma unroll
      for (int w = 0; w < 4; w++) v = fmaxf(v, red[w * 32 + h]);
      mh[mt][r] = v;
    }
  float ps[2][4];
#pragma unroll
  for (int mt = 0; mt < 2; mt++)
#pragma unroll
    for (int r = 0; r < 4; r++) {
      float acc = 0.f;
#pragma unroll
      for (int c = 0; c < 4; c++) {
        float e = fast_exp2(sc[c][mt][r] - mh[mt][r]);
        sc[c][mt][r] = e;
        acc += e;
      }
      RED16_SUM(acc);
      ps[mt][r] = acc;
    }
  if (l16 == 0) {
#pragma unroll
    for (int mt = 0; mt < 2; mt++)
#pragma unroll
      for (int r = 0; r < 4; r++)
        red2[wave * 32 + mt * 16 + quad * 4 + r] = ps[mt][r];
  }
  __syncthreads();
  float inv[2][4];
#pragma unroll
  for (int mt = 0; mt < 2; mt++)
#pragma unroll
    for (int r = 0; r < 4; r++) {
      int h = mt * 16 + quad * 4 + r;
      float dd = fast_exp2(sink_s[h] - mh[mt][r]);
#pragma unroll
      for (int w = 0; w < 4; w++) dd += red2[w * 32 + h];
      inv[mt][r] = 1.0f / dd;
    }
  // write P (bf16, unnormalized) to pbuf [head][col] — packed conversions
#pragma unroll
  for (int c = 0; c < 4; c++)
#pragma unroll
    for (int mt = 0; mt < 2; mt++) {
      int col = c * 64 + wave * 16 + l16;
      unsigned short* pb = &pbuf[(mt * 16 + quad * 4) * PB_STRIDE + col];
      unsigned p01 = pk_bf16(sc[c][mt][0], sc[c][mt][1]);
      unsigned p23 = pk_bf16(sc[c][mt][2], sc[c][mt][3]);
      pb[0] = (unsigned short)p01;
      pb[PB_STRIDE] = (unsigned short)(p01 >> 16);
      pb[2 * PB_STRIDE] = (unsigned short)p23;
      pb[3 * PB_STRIDE] = (unsigned short)(p23 >> 16);
    }
  __syncthreads();  // pbuf + V0 visible

  // ---- Phase 3: O = P V with register-prefetch pipeline ----
  floatx4 oacc[2][2];
#pragma unroll
  for (int mt = 0; mt < 2; mt++)
#pragma unroll
    for (int nt = 0; nt < 2; nt++)
      oacc[mt][nt] = (floatx4){0.f, 0.f, 0.f, 0.f};

  pv_chunk(pbuf, kvbuf, 0, wave, quad, l16, oacc);
  __syncthreads();
  v_write(kvbuf, v1, tid);
  VR v2 = v_load(kvb, topk_s, 2, tid);
  __syncthreads();

  pv_chunk(pbuf, kvbuf, 1, wave, quad, l16, oacc);
  __syncthreads();
  v_write(kvbuf, v2, tid);
  VR v3 = v_load(kvb, topk_s, 3, tid);
  __syncthreads();

  pv_chunk(pbuf, kvbuf, 2, wave, quad, l16, oacc);
  __syncthreads();
  v_write(kvbuf, v3, tid);
  __syncthreads();

  pv_chunk(pbuf, kvbuf, 3, wave, quad, l16, oacc);

  // ---- Phase 4: epilogue ----
  {
    float* op = out + (size_t)s * (NH * DH);
#pragma unroll
    for (int mt = 0; mt < 2; mt++)
#pragma unroll
      for (int nt = 0; nt < 2; nt++)
#pragma unroll
        for (int r4 = 0; r4 < 4; r4++) {
          int h = mt * 16 + quad * 4 + r4;
          int d = wave * 32 + nt * 16 + l16;
          op[h * DH + d] = oacc[mt][nt][r4] * inv[mt][r4];
        }
  }
}

extern "C" void kernel_launch(void* const* d_in, const int* in_sizes, int n_in,
                              void* d_out, int out_size, void* d_ws, size_t ws_size,
                              hipStream_t stream) {
  (void)in_sizes; (void)n_in; (void)out_size; (void)ws_size;
  const float* q    = (const float*)d_in[0];
  const float* kv   = (const float*)d_in[1];
  const float* sink = (const float*)d_in[2];
  const int*   topk = (const int*)d_in[3];
  float* out = (float*)d_out;
  unsigned short* kvb = (unsigned short*)d_ws;  // 2 MB bf16 KV

  kv_to_bf16<<<dim3(1024), dim3(256), 0, stream>>>(kv, kvb);
  sparse_attn_kernel<<<dim3(SQ), dim3(256), 0, stream>>>(q, kvb, sink, topk, out);
}